// Round 1
// baseline (85767.834 us; speedup 1.0000x reference)
//
#include <hip/hip_runtime.h>
#include <cstdint>
#include <cstddef>

// BiLSTM-CRF forward + Viterbi decode, T=4096, E=300, H2=256, K=32.
// Pipeline:
//   K1 zx_gemm      : zx[t] = Wih @ embed[token] + b  (both directions, batched GEMM)
//   K2 lstm_kernel  : 2 persistent blocks (fwd/bwd), Whh in VGPRs, h in LDS,
//                     fused W_out projection -> featF/featB (hf/hb never stored)
//   K3 viterbi_fwd  : sequential max-plus recursion, backpointers (u8)
//   K4 vit_compose  : 32-step chunk map composition (parallel backtrace, part 1)
//   K5 vit_backtrace: boundary walk + parallel chunk expansion -> d_out
// ws layout (floats): zxF[4096*1024] zxB[4096*1024] featF[4096*32] featB[4096*32]
// then bytes: bestIdx(int,64B slot), bptr u8[4096*32], fmap u8[128*32]  (~34.8 MB)

#define T_LEN 4096
#define E_DIM 300
#define H2 256
#define G4 1024
#define KTAGS 32
#define START_TAG 30
#define STOP_TAG 31
#define NEGV (-10000.0f)

template <int CTRL>
__device__ __forceinline__ float dpp_xor_add(float x) {
  // quad_perm butterfly add (stays on VALU; no LDS-pipe swizzle)
  int v = __builtin_amdgcn_update_dpp(0, __float_as_int(x), CTRL, 0xF, 0xF, true);
  return x + __int_as_float(v);
}

__device__ __forceinline__ float fast_sigmoid(float x) {
  return __builtin_amdgcn_rcpf(1.0f + __expf(-x));
}
__device__ __forceinline__ float fast_tanh(float x) {
  // 1 - 2/(e^{2x}+1); saturates correctly for |x| large
  return 1.0f - 2.0f * __builtin_amdgcn_rcpf(__expf(2.0f * x) + 1.0f);
}

// ---------------- K1: input projection GEMM ----------------
__global__ __launch_bounds__(256) void zx_gemm(
    const int* __restrict__ sent, const float* __restrict__ embed,
    const float* __restrict__ Wih_f, const float* __restrict__ b_f,
    const float* __restrict__ Wih_b, const float* __restrict__ b_b,
    float* __restrict__ zxF, float* __restrict__ zxB)
{
  const int dir = blockIdx.y;
  const int t0 = blockIdx.x * 8;
  const float* __restrict__ Wih = dir ? Wih_b : Wih_f;
  const float* __restrict__ bias = dir ? b_b : b_f;
  float* __restrict__ zx = dir ? zxB : zxF;

  __shared__ __align__(16) float xs[8 * E_DIM];
  const int tid = threadIdx.x;
  for (int ti = 0; ti < 8; ++ti) {
    int p = t0 + ti;
    int tok = sent[dir ? (T_LEN - 1 - p) : p];
    const float* er = embed + (size_t)tok * E_DIM;
    for (int k = tid; k < E_DIM; k += 256) xs[ti * E_DIM + k] = er[k];
  }
  __syncthreads();

  const int r = tid;  // 0..255, handles gate rows r, r+256, r+512, r+768
  float acc[4][8];
#pragma unroll
  for (int g = 0; g < 4; ++g) {
    float bv = bias[g * 256 + r];
#pragma unroll
    for (int ti = 0; ti < 8; ++ti) acc[g][ti] = bv;
  }
  const float4* w0p = (const float4*)(Wih + (size_t)(r) * E_DIM);
  const float4* w1p = (const float4*)(Wih + (size_t)(256 + r) * E_DIM);
  const float4* w2p = (const float4*)(Wih + (size_t)(512 + r) * E_DIM);
  const float4* w3p = (const float4*)(Wih + (size_t)(768 + r) * E_DIM);
  for (int k4 = 0; k4 < E_DIM / 4; ++k4) {
    float4 w0 = w0p[k4], w1 = w1p[k4], w2 = w2p[k4], w3 = w3p[k4];
#pragma unroll
    for (int ti = 0; ti < 8; ++ti) {
      float4 x4 = *(const float4*)(xs + ti * E_DIM + k4 * 4);
      acc[0][ti] += w0.x * x4.x + w0.y * x4.y + w0.z * x4.z + w0.w * x4.w;
      acc[1][ti] += w1.x * x4.x + w1.y * x4.y + w1.z * x4.z + w1.w * x4.w;
      acc[2][ti] += w2.x * x4.x + w2.y * x4.y + w2.z * x4.z + w2.w * x4.w;
      acc[3][ti] += w3.x * x4.x + w3.y * x4.y + w3.z * x4.z + w3.w * x4.w;
    }
  }
#pragma unroll
  for (int g = 0; g < 4; ++g)
#pragma unroll
    for (int ti = 0; ti < 8; ++ti)
      zx[(size_t)(t0 + ti) * G4 + g * 256 + r] = acc[g][ti];
}

// ---------------- K2: persistent bidirectional LSTM ----------------
__global__ __launch_bounds__(1024, 4) void lstm_kernel(
    const float* __restrict__ Whh_f, const float* __restrict__ Whh_b,
    const float* __restrict__ h0, const float* __restrict__ c0,
    const float* __restrict__ W_out,
    const float* __restrict__ zxF, const float* __restrict__ zxB,
    float* __restrict__ featF, float* __restrict__ featB)
{
  const int d = blockIdx.x;  // 0 = forward, 1 = backward
  const float* __restrict__ Whh = d ? Whh_b : Whh_f;
  const float* __restrict__ zx = d ? zxB : zxF;
  float* __restrict__ feat = d ? featB : featF;

  const int tid = threadIdx.x;
  const int wv = tid >> 6;
  const int ln = tid & 63;
  const int rowgrp = ln >> 2;   // 16 row-groups per wave
  const int kpart = ln & 3;     // 4-way split of k=256
  const int R0 = wv * 64 + rowgrp * 4;
  const int k0 = kpart * 64;
  const int myrow = R0 + kpart;

  __shared__ __align__(16) float hA[H2];
  __shared__ __align__(16) float hB[H2];
  __shared__ float zbuf[G4];

  // Whh fragment: 4 rows x 64 k -> 64 float4 = 256 VGPRs, resident all 4096 steps
  float4 wreg[64];
#pragma unroll
  for (int rr = 0; rr < 4; ++rr) {
    const float* wp = Whh + (size_t)(R0 + rr) * H2 + k0;
#pragma unroll
    for (int i = 0; i < 16; ++i) wreg[rr * 16 + i] = *(const float4*)(wp + i * 4);
  }

  float c = 0.0f;
  if (tid < H2) {
    c = c0[d * H2 + tid];
    hA[tid] = h0[d * H2 + tid];
  }

  // fused output projection: thread -> (row fr of W_out, 8-wide k chunk)
  const int fr = tid >> 5;
  const int fp = tid & 31;
  float wo[8];
#pragma unroll
  for (int i = 0; i < 8; ++i) wo[i] = W_out[fr * 512 + d * H2 + fp * 8 + i];

  __syncthreads();

  float zpre = zx[myrow];  // prefetch for t=0

  auto step = [&](const float* hin, float* hout, int t) {
    float zcur = zpre;
    int tn = (t + 1 < T_LEN) ? (t + 1) : t;
    zpre = zx[(size_t)tn * G4 + myrow];  // prefetch next step

    float a0 = 0.f, a1 = 0.f, a2 = 0.f, a3 = 0.f;
    const float* hk = hin + k0;
#pragma unroll
    for (int i = 0; i < 16; ++i) {
      float4 hv = *(const float4*)(hk + i * 4);
      float4 w0 = wreg[i], w1 = wreg[16 + i], w2 = wreg[32 + i], w3 = wreg[48 + i];
      a0 += w0.x * hv.x; a0 += w0.y * hv.y; a0 += w0.z * hv.z; a0 += w0.w * hv.w;
      a1 += w1.x * hv.x; a1 += w1.y * hv.y; a1 += w1.z * hv.z; a1 += w1.w * hv.w;
      a2 += w2.x * hv.x; a2 += w2.y * hv.y; a2 += w2.z * hv.z; a2 += w2.w * hv.w;
      a3 += w3.x * hv.x; a3 += w3.y * hv.y; a3 += w3.z * hv.z; a3 += w3.w * hv.w;
    }
    // reduce the 4-way k split inside each quad (VALU-only DPP butterflies)
    a0 = dpp_xor_add<0xB1>(a0); a0 = dpp_xor_add<0x4E>(a0);
    a1 = dpp_xor_add<0xB1>(a1); a1 = dpp_xor_add<0x4E>(a1);
    a2 = dpp_xor_add<0xB1>(a2); a2 = dpp_xor_add<0x4E>(a2);
    a3 = dpp_xor_add<0xB1>(a3); a3 = dpp_xor_add<0x4E>(a3);
    float av = (kpart == 0) ? a0 : (kpart == 1) ? a1 : (kpart == 2) ? a2 : a3;
    zbuf[myrow] = av + zcur;
    __syncthreads();

    if (tid < H2) {
      float ig = zbuf[tid];
      float fg = zbuf[H2 + tid];
      float gg = zbuf[2 * H2 + tid];
      float og = zbuf[3 * H2 + tid];
      float si = fast_sigmoid(ig);
      float sf = fast_sigmoid(fg);
      float so = fast_sigmoid(og);
      c = sf * c + si * fast_tanh(gg);
      hout[tid] = so * fast_tanh(c);
    }
    __syncthreads();

    // fused feature: feat[t][fr] = sum_k W_out[fr][d*256+k] * h[k]
    {
      const float* hh = hout + fp * 8;
      float4 h0v = *(const float4*)(hh);
      float4 h1v = *(const float4*)(hh + 4);
      float s = wo[0] * h0v.x + wo[1] * h0v.y + wo[2] * h0v.z + wo[3] * h0v.w +
                wo[4] * h1v.x + wo[5] * h1v.y + wo[6] * h1v.z + wo[7] * h1v.w;
      s += __shfl_xor(s, 1);
      s += __shfl_xor(s, 2);
      s += __shfl_xor(s, 4);
      s += __shfl_xor(s, 8);
      s += __shfl_xor(s, 16);
      if (fp == 0) {
        int tpos = d ? (T_LEN - 1 - t) : t;
        feat[(size_t)tpos * KTAGS + fr] = s;
      }
    }
  };

  for (int t = 0; t < T_LEN; t += 2) {  // unroll-2 for static LDS double-buffer
    step(hA, hB, t);
    step(hB, hA, t + 1);
  }
}

// ---------------- K3: Viterbi forward recursion ----------------
__global__ __launch_bounds__(1024) void viterbi_fwd(
    const float* __restrict__ featF, const float* __restrict__ featB,
    const float* __restrict__ b_out, const float* __restrict__ trans,
    unsigned char* __restrict__ bptr, float* __restrict__ score_out,
    int* __restrict__ best_out)
{
  const int tid = threadIdx.x;
  const int i = tid >> 5;  // new tag
  const int j = tid & 31;  // prev tag
  const float treg = trans[i * 32 + j];
  const float breg = b_out[i];
  __shared__ float fvA[KTAGS], fvB[KTAGS];
  if (tid < KTAGS) fvA[tid] = (tid == START_TAG) ? 0.0f : NEGV;
  __syncthreads();
  float pfF = featF[i], pfB = featB[i];

  auto vstep = [&](const float* fin, float* fout, int t) {
    float fF = pfF, fB = pfB;
    int tn = (t + 1 < T_LEN) ? (t + 1) : t;
    pfF = featF[(size_t)tn * KTAGS + i];
    pfB = featB[(size_t)tn * KTAGS + i];
    float v = fin[j] + treg;
    int bj = j;
#pragma unroll
    for (int m = 1; m < 32; m <<= 1) {  // first-index argmax (numpy tie rule)
      float ov = __shfl_xor(v, m);
      int oj = __shfl_xor(bj, m);
      if (ov > v || (ov == v && oj < bj)) { v = ov; bj = oj; }
    }
    if (j == 0) {
      fout[i] = v + fF + fB + breg;
      bptr[(size_t)t * KTAGS + i] = (unsigned char)bj;
    }
    __syncthreads();
  };

  for (int t = 0; t < T_LEN; t += 2) { vstep(fvA, fvB, t); vstep(fvB, fvA, t + 1); }

  if (tid < KTAGS) {  // terminal: fv + transitions[STOP]
    float v = fvA[tid] + trans[STOP_TAG * 32 + tid];
    int bj = tid;
#pragma unroll
    for (int m = 1; m < 32; m <<= 1) {
      float ov = __shfl_xor(v, m);
      int oj = __shfl_xor(bj, m);
      if (ov > v || (ov == v && oj < bj)) { v = ov; bj = oj; }
    }
    if (tid == 0) { score_out[0] = v; best_out[0] = bj; }
  }
}

// ---------------- K4: compose 32-step backtrace maps ----------------
__global__ __launch_bounds__(64) void vit_compose(
    const unsigned char* __restrict__ bptr, unsigned char* __restrict__ fmap)
{
  const int m = blockIdx.x;  // chunk 0..127
  __shared__ unsigned char B[32 * 32];
  const int tid = threadIdx.x;
  const uint32_t* src = (const uint32_t*)(bptr + (size_t)m * 1024);
  uint32_t* dstw = (uint32_t*)B;
  for (int idx = tid; idx < 256; idx += 64) dstw[idx] = src[idx];
  __syncthreads();
  if (tid < 32) {
    int y = tid;
#pragma unroll
    for (int tt = 31; tt >= 0; --tt) y = B[tt * 32 + y];
    fmap[m * 32 + tid] = (unsigned char)y;  // tag@(m*32+31) -> tag@(m*32-1)
  }
}

// ---------------- K5: boundary walk + parallel expansion ----------------
__global__ __launch_bounds__(256) void vit_backtrace(
    const unsigned char* __restrict__ bptr, const unsigned char* __restrict__ fmap,
    const int* __restrict__ best, float* __restrict__ path_out)
{
  __shared__ unsigned char F[128 * 32];
  __shared__ unsigned char bound[128];
  const int tid = threadIdx.x;
  const uint32_t* src = (const uint32_t*)fmap;
  uint32_t* dstw = (uint32_t*)F;
  for (int idx = tid; idx < 1024; idx += 256) dstw[idx] = src[idx];
  __syncthreads();
  if (tid == 0) {
    int y = best[0];
    bound[127] = (unsigned char)y;  // tag@4095
    for (int m = 127; m >= 1; --m) {
      y = F[m * 32 + y];
      bound[m - 1] = (unsigned char)y;  // tag@(m*32-1)
    }
  }
  __syncthreads();
  if (tid < 128) {
    const int m = tid;
    int y = bound[m];  // tag at position m*32+31
    path_out[m * 32 + 31] = (float)y;
    for (int tt = 30; tt >= 0; --tt) {
      y = bptr[(size_t)(m * 32 + tt + 1) * 32 + y];  // tag(t)=bptr[t+1][tag(t+1)]
      path_out[m * 32 + tt] = (float)y;
    }
  }
}

extern "C" void kernel_launch(void* const* d_in, const int* in_sizes, int n_in,
                              void* d_out, int out_size, void* d_ws, size_t ws_size,
                              hipStream_t stream)
{
  const int* sent    = (const int*)d_in[0];
  const float* embed = (const float*)d_in[1];
  const float* Wih_f = (const float*)d_in[2];
  const float* Whh_f = (const float*)d_in[3];
  const float* b_f   = (const float*)d_in[4];
  const float* Wih_b = (const float*)d_in[5];
  const float* Whh_b = (const float*)d_in[6];
  const float* b_b   = (const float*)d_in[7];
  const float* W_out = (const float*)d_in[8];
  const float* b_out = (const float*)d_in[9];
  const float* trans = (const float*)d_in[10];
  const float* h0    = (const float*)d_in[11];
  const float* c0    = (const float*)d_in[12];

  float* W = (float*)d_ws;
  float* zxF = W;
  float* zxB = W + (size_t)T_LEN * G4;
  float* featF = W + 2 * (size_t)T_LEN * G4;
  float* featB = featF + (size_t)T_LEN * KTAGS;
  char* base = (char*)(featB + (size_t)T_LEN * KTAGS);
  int* bestIdx = (int*)base;                       // 64-byte slot
  unsigned char* bptr = (unsigned char*)(base + 64);
  unsigned char* fmap = bptr + (size_t)T_LEN * KTAGS;

  float* out = (float*)d_out;  // out[0]=path_score, out[1..4096]=path tags

  zx_gemm<<<dim3(T_LEN / 8, 2), 256, 0, stream>>>(sent, embed, Wih_f, b_f, Wih_b, b_b, zxF, zxB);
  lstm_kernel<<<2, 1024, 0, stream>>>(Whh_f, Whh_b, h0, c0, W_out, zxF, zxB, featF, featB);
  viterbi_fwd<<<1, 1024, 0, stream>>>(featF, featB, b_out, trans, bptr, out, bestIdx);
  vit_compose<<<128, 64, 0, stream>>>(bptr, fmap);
  vit_backtrace<<<1, 256, 0, stream>>>(bptr, fmap, bestIdx, out + 1);
}

// Round 2
// 15073.268 us; speedup vs baseline: 5.6901x; 5.6901x over previous
//
#include <hip/hip_runtime.h>
#include <hip/hip_bf16.h>
#include <cstdint>
#include <cstddef>

// BiLSTM-CRF forward + Viterbi decode, T=4096, E=300, H2=256, K=32.
//   K1 zx_gemm   : zx[t] = Wih @ embed[token] + b (both dirs, batched)
//   K2 lstm_kernel: 4 CUs per direction, Whh weight-stationary in VGPRs
//                   (256KB/CU = 128 VGPR/thread @512thr, launch_bounds(512,2)
//                   -> 256-VGPR budget; 1024-thr/128-cap caused the R1 spill).
//                   Per-step 64-float h-segment exchange via L2 + agent-scope
//                   acquire/release progress flags; workers elected per-XCD
//                   via HW_REG_XCC_ID so sync stays on one XCD's L2.
//   K3 feat_kernel: feats = [hf|hb] @ W_out^T + b_out  (h history in bf16)
//   K4 viterbi_fwd, K5 compose, K6 backtrace: as before.

#define T_LEN 4096
#define E_DIM 300
#define H2 256
#define G4 1024
#define KTAGS 32
#define START_TAG 30
#define STOP_TAG 31
#define NEGV (-10000.0f)

__device__ __forceinline__ float fast_sigmoid(float x) {
  return __builtin_amdgcn_rcpf(1.0f + __expf(-x));
}
__device__ __forceinline__ float fast_tanh(float x) {
  return 1.0f - 2.0f * __builtin_amdgcn_rcpf(__expf(2.0f * x) + 1.0f);
}

template <int CTRL>
__device__ __forceinline__ float row_ror_add(float x) {
  // v_add with DPP row_ror — reduction stays on the VALU pipe (no LDS swizzle)
  int v = __builtin_amdgcn_update_dpp(0, __float_as_int(x), CTRL, 0xF, 0xF, true);
  return x + __int_as_float(v);
}

// ---------------- K1: input projection GEMM ----------------
__global__ __launch_bounds__(256) void zx_gemm(
    const int* __restrict__ sent, const float* __restrict__ embed,
    const float* __restrict__ Wih_f, const float* __restrict__ b_f,
    const float* __restrict__ Wih_b, const float* __restrict__ b_b,
    float* __restrict__ zxF, float* __restrict__ zxB)
{
  const int dir = blockIdx.y;
  const int t0 = blockIdx.x * 8;
  const float* __restrict__ Wih = dir ? Wih_b : Wih_f;
  const float* __restrict__ bias = dir ? b_b : b_f;
  float* __restrict__ zx = dir ? zxB : zxF;

  __shared__ __align__(16) float xs[8 * E_DIM];
  const int tid = threadIdx.x;
  for (int ti = 0; ti < 8; ++ti) {
    int p = t0 + ti;
    int tok = sent[dir ? (T_LEN - 1 - p) : p];
    const float* er = embed + (size_t)tok * E_DIM;
    for (int k = tid; k < E_DIM; k += 256) xs[ti * E_DIM + k] = er[k];
  }
  __syncthreads();

  const int r = tid;
  float acc[4][8];
#pragma unroll
  for (int g = 0; g < 4; ++g) {
    float bv = bias[g * 256 + r];
#pragma unroll
    for (int ti = 0; ti < 8; ++ti) acc[g][ti] = bv;
  }
  const float4* w0p = (const float4*)(Wih + (size_t)(r) * E_DIM);
  const float4* w1p = (const float4*)(Wih + (size_t)(256 + r) * E_DIM);
  const float4* w2p = (const float4*)(Wih + (size_t)(512 + r) * E_DIM);
  const float4* w3p = (const float4*)(Wih + (size_t)(768 + r) * E_DIM);
  for (int k4 = 0; k4 < E_DIM / 4; ++k4) {
    float4 w0 = w0p[k4], w1 = w1p[k4], w2 = w2p[k4], w3 = w3p[k4];
#pragma unroll
    for (int ti = 0; ti < 8; ++ti) {
      float4 x4 = *(const float4*)(xs + ti * E_DIM + k4 * 4);
      acc[0][ti] += w0.x * x4.x + w0.y * x4.y + w0.z * x4.z + w0.w * x4.w;
      acc[1][ti] += w1.x * x4.x + w1.y * x4.y + w1.z * x4.z + w1.w * x4.w;
      acc[2][ti] += w2.x * x4.x + w2.y * x4.y + w2.z * x4.z + w2.w * x4.w;
      acc[3][ti] += w3.x * x4.x + w3.y * x4.y + w3.z * x4.z + w3.w * x4.w;
    }
  }
#pragma unroll
  for (int g = 0; g < 4; ++g)
#pragma unroll
    for (int ti = 0; ti < 8; ++ti)
      zx[(size_t)(t0 + ti) * G4 + g * 256 + r] = acc[g][ti];
}

// ---------------- K2: 4-CU-per-direction persistent LSTM ----------------
// ctl layout (ints): [0..7]=xcdCnt  [8]=dirCnt  [16..23]=xcdDir  [24..31]=prog
__global__ __launch_bounds__(512, 2) void lstm_kernel(
    const float* __restrict__ Whh_f, const float* __restrict__ Whh_b,
    const float* __restrict__ h0, const float* __restrict__ c0,
    const float* __restrict__ zxF, const float* __restrict__ zxB,
    float* __restrict__ hxchg, __hip_bfloat16* __restrict__ hhF,
    __hip_bfloat16* __restrict__ hhB, int* __restrict__ ctl)
{
  __shared__ int sh_dir, sh_role;
  const int tid = threadIdx.x;

  if (tid == 0) {
    // HW_REG_XCC_ID = 20, offset 0, size 4  -> imm = 20 | (3<<11)
    int xcd = (int)(__builtin_amdgcn_s_getreg(20 | (3 << 11)) & 7);
    int* xcdCnt = ctl;
    int* dirCnt = ctl + 8;
    int* xcdDir = ctl + 16;
    int r = atomicAdd(&xcdCnt[xcd], 1);
    if (r == 3) {  // 4th block on this XCD claims a direction for the XCD
      int idx = atomicAdd(dirCnt, 1);
      __hip_atomic_store(&xcdDir[xcd], (idx < 2) ? (idx + 1) : 3,
                         __ATOMIC_RELEASE, __HIP_MEMORY_SCOPE_AGENT);
    }
    int dir = -1;
    if (r < 4) {
      int v = 0;
      long g = 0;
      do {
        v = __hip_atomic_load(&xcdDir[xcd], __ATOMIC_ACQUIRE, __HIP_MEMORY_SCOPE_AGENT);
      } while (v == 0 && ++g < (1L << 31));
      if (v >= 1 && v <= 2) dir = v - 1;
    }
    sh_dir = dir;
    sh_role = r;
  }
  __syncthreads();
  const int d = sh_dir;
  const int r = sh_role;
  if (d < 0) return;  // non-elected block: whole block exits

  const float* __restrict__ Whh = d ? Whh_b : Whh_f;
  const float* __restrict__ zxd = d ? zxB : zxF;
  __hip_bfloat16* __restrict__ hh = d ? hhB : hhF;
  int* __restrict__ prog = ctl + 24;

  const int kslice = tid & 15;   // 16 k-slices x 16 floats
  const int rgroup = tid >> 4;   // 32 row-groups x 8 rows

  // padded h layout: slice s at floats [s*20, s*20+16)  (stride 20 breaks the
  // 16-dword bank stride; b128 reads land ~2-way = free per m136)
#define PADIDX(k) (((k) >> 4) * 20 + ((k) & 15))
  __shared__ __align__(16) float hA[16 * 20];
  __shared__ __align__(16) float hB[16 * 20];
  __shared__ __align__(16) float zbuf[256];

  // weights: 8 rows x 16 k = 32 float4 = 128 VGPR, resident all 4096 steps
  float4 wreg[32];
#pragma unroll
  for (int m = 0; m < 8; ++m) {
    int lr = rgroup * 8 + m;                       // local row 0..255
    int grow = (lr >> 6) * 256 + r * 64 + (lr & 63);  // global gate row
    const float* wp = Whh + (size_t)grow * H2 + kslice * 16;
#pragma unroll
    for (int i = 0; i < 4; ++i) wreg[m * 4 + i] = *(const float4*)(wp + i * 4);
  }

  float c = 0.0f;
  float zx4[4] = {0.f, 0.f, 0.f, 0.f};
  if (tid < H2) hA[PADIDX(tid)] = h0[d * H2 + tid];
  if (tid < 64) {
    c = c0[d * H2 + r * 64 + tid];
#pragma unroll
    for (int g = 0; g < 4; ++g)
      zx4[g] = zxd[(size_t)0 * G4 + g * 256 + r * 64 + tid];
  }
  __syncthreads();

  auto step = [&](const float* hin, float* hout, int t) {
    // ---- matvec: z_partial = Whh_slice @ h ----
    float4 h4[4];
    const float* hp = hin + kslice * 20;
#pragma unroll
    for (int i = 0; i < 4; ++i) h4[i] = *(const float4*)(hp + i * 4);
    float acc[8];
#pragma unroll
    for (int m = 0; m < 8; ++m) {
      float a = 0.f;
#pragma unroll
      for (int i = 0; i < 4; ++i) {
        float4 w = wreg[m * 4 + i];
        a += w.x * h4[i].x; a += w.y * h4[i].y;
        a += w.z * h4[i].z; a += w.w * h4[i].w;
      }
      acc[m] = a;
    }
    // reduce over 16 k-slices (DPP row rotations, VALU pipe)
#pragma unroll
    for (int m = 0; m < 8; ++m) {
      acc[m] = row_ror_add<0x128>(acc[m]);
      acc[m] = row_ror_add<0x124>(acc[m]);
      acc[m] = row_ror_add<0x122>(acc[m]);
      acc[m] = row_ror_add<0x121>(acc[m]);
    }
    if (kslice == 0) {
      float4 w0 = {acc[0], acc[1], acc[2], acc[3]};
      float4 w1 = {acc[4], acc[5], acc[6], acc[7]};
      *(float4*)&zbuf[rgroup * 8] = w0;
      *(float4*)&zbuf[rgroup * 8 + 4] = w1;
    }
    __syncthreads();

    if (tid < 64) {
      // ---- gates + publish (wave 0) ----
      float zi = zbuf[tid] + zx4[0];
      float zf = zbuf[64 + tid] + zx4[1];
      float zg = zbuf[128 + tid] + zx4[2];
      float zo = zbuf[192 + tid] + zx4[3];
      c = fast_sigmoid(zf) * c + fast_sigmoid(zi) * fast_tanh(zg);
      float hv = fast_sigmoid(zo) * fast_tanh(c);
      int k = r * 64 + tid;
      hout[PADIDX(k)] = hv;                                  // local LDS
      hxchg[(d * 2 + (t & 1)) * 256 + k] = hv;               // fp32 exchange
      hh[(size_t)t * H2 + k] = (__hip_bfloat16)hv;           // bf16 history
      __threadfence();                                       // drain stores
      if (tid == 0)
        __hip_atomic_store(&prog[d * 4 + r], t + 1,
                           __ATOMIC_RELAXED, __HIP_MEMORY_SCOPE_AGENT);
      // prefetch zx for t+1
      if (t + 1 < T_LEN) {
#pragma unroll
        for (int g = 0; g < 4; ++g)
          zx4[g] = zxd[(size_t)(t + 1) * G4 + g * 256 + r * 64 + tid];
      }
    } else if (tid < 128 && t + 1 < T_LEN) {
      // ---- remote fetch (wave 1), overlaps wave 0's gate math ----
      int i = tid - 64;
      const float* xb = hxchg + (d * 2 + (t & 1)) * 256;
      for (int j = 0; j < 4; ++j) {
        if (j == r) continue;
        long g = 0;
        while (__hip_atomic_load(&prog[d * 4 + j], __ATOMIC_ACQUIRE,
                                 __HIP_MEMORY_SCOPE_AGENT) < t + 1) {
          if (++g > (1L << 30)) break;
        }
        int k = j * 64 + i;
        hout[PADIDX(k)] = xb[k];
      }
    }
    __syncthreads();
  };

  for (int t = 0; t < T_LEN; t += 2) {
    step(hA, hB, t);
    step(hB, hA, t + 1);
  }
}

// ---------------- K3: feats = [hf|hb] @ W_out^T + b_out ----------------
__global__ __launch_bounds__(256) void feat_kernel(
    const __hip_bfloat16* __restrict__ hhF, const __hip_bfloat16* __restrict__ hhB,
    const float* __restrict__ W_out, const float* __restrict__ b_out,
    float* __restrict__ feats)
{
  const int p0 = blockIdx.x * 8;
  const int tid = threadIdx.x;
  __shared__ float hs[8 * 520];  // 512 + 8 pad (one per 64-chunk)
#define HIDX(pos, k) ((pos) * 520 + (k) + ((k) >> 6))
  for (int idx = tid; idx < 2048; idx += 256) {
    int pos = idx >> 8, k = idx & 255;
    hs[HIDX(pos, k)] = (float)hhF[(size_t)(p0 + pos) * H2 + k];
    hs[HIDX(pos, 256 + k)] = (float)hhB[(size_t)(T_LEN - 1 - (p0 + pos)) * H2 + k];
  }
  __syncthreads();

  const int tag = tid >> 3;  // 32 tags
  const int kc = tid & 7;    // 8 chunks of 64
  float4 w4[16];
  const float4* wp = (const float4*)(W_out + tag * 512 + kc * 64);
#pragma unroll
  for (int i = 0; i < 16; ++i) w4[i] = wp[i];
  const float bo = b_out[tag];

#pragma unroll
  for (int pos = 0; pos < 8; ++pos) {
    const float* hp = hs + pos * 520 + kc * 64 + kc;  // k>>6 == kc in-chunk
    float a = 0.f;
#pragma unroll
    for (int i = 0; i < 16; ++i) {
      float4 w = w4[i];
      a += w.x * hp[i * 4] + w.y * hp[i * 4 + 1] + w.z * hp[i * 4 + 2] + w.w * hp[i * 4 + 3];
    }
    a += __shfl_xor(a, 1);
    a += __shfl_xor(a, 2);
    a += __shfl_xor(a, 4);
    if (kc == 0) feats[(size_t)(p0 + pos) * KTAGS + tag] = a + bo;
  }
}

// ---------------- K4: Viterbi forward recursion ----------------
__global__ __launch_bounds__(1024) void viterbi_fwd(
    const float* __restrict__ feats, const float* __restrict__ trans,
    unsigned char* __restrict__ bptr, float* __restrict__ score_out,
    int* __restrict__ best_out)
{
  const int tid = threadIdx.x;
  const int i = tid >> 5;  // new tag
  const int j = tid & 31;  // prev tag
  const float treg = trans[i * 32 + j];
  __shared__ float fvA[KTAGS], fvB[KTAGS];
  if (tid < KTAGS) fvA[tid] = (tid == START_TAG) ? 0.0f : NEGV;
  __syncthreads();
  float pf = feats[i];

  auto vstep = [&](const float* fin, float* fout, int t) {
    float fF = pf;
    int tn = (t + 1 < T_LEN) ? (t + 1) : t;
    pf = feats[(size_t)tn * KTAGS + i];
    float v = fin[j] + treg;
    int bj = j;
#pragma unroll
    for (int m = 1; m < 32; m <<= 1) {  // first-index argmax (numpy tie rule)
      float ov = __shfl_xor(v, m);
      int oj = __shfl_xor(bj, m);
      if (ov > v || (ov == v && oj < bj)) { v = ov; bj = oj; }
    }
    if (j == 0) {
      fout[i] = v + fF;
      bptr[(size_t)t * KTAGS + i] = (unsigned char)bj;
    }
    __syncthreads();
  };

  for (int t = 0; t < T_LEN; t += 2) { vstep(fvA, fvB, t); vstep(fvB, fvA, t + 1); }

  if (tid < KTAGS) {
    float v = fvA[tid] + trans[STOP_TAG * 32 + tid];
    int bj = tid;
#pragma unroll
    for (int m = 1; m < 32; m <<= 1) {
      float ov = __shfl_xor(v, m);
      int oj = __shfl_xor(bj, m);
      if (ov > v || (ov == v && oj < bj)) { v = ov; bj = oj; }
    }
    if (tid == 0) { score_out[0] = v; best_out[0] = bj; }
  }
}

// ---------------- K5: compose 32-step backtrace maps ----------------
__global__ __launch_bounds__(64) void vit_compose(
    const unsigned char* __restrict__ bptr, unsigned char* __restrict__ fmap)
{
  const int m = blockIdx.x;
  __shared__ unsigned char B[32 * 32];
  const int tid = threadIdx.x;
  const uint32_t* src = (const uint32_t*)(bptr + (size_t)m * 1024);
  uint32_t* dstw = (uint32_t*)B;
  for (int idx = tid; idx < 256; idx += 64) dstw[idx] = src[idx];
  __syncthreads();
  if (tid < 32) {
    int y = tid;
#pragma unroll
    for (int tt = 31; tt >= 0; --tt) y = B[tt * 32 + y];
    fmap[m * 32 + tid] = (unsigned char)y;
  }
}

// ---------------- K6: boundary walk + parallel expansion ----------------
__global__ __launch_bounds__(256) void vit_backtrace(
    const unsigned char* __restrict__ bptr, const unsigned char* __restrict__ fmap,
    const int* __restrict__ best, float* __restrict__ path_out)
{
  __shared__ unsigned char F[128 * 32];
  __shared__ unsigned char bound[128];
  const int tid = threadIdx.x;
  const uint32_t* src = (const uint32_t*)fmap;
  uint32_t* dstw = (uint32_t*)F;
  for (int idx = tid; idx < 1024; idx += 256) dstw[idx] = src[idx];
  __syncthreads();
  if (tid == 0) {
    int y = best[0];
    bound[127] = (unsigned char)y;
    for (int m = 127; m >= 1; --m) {
      y = F[m * 32 + y];
      bound[m - 1] = (unsigned char)y;
    }
  }
  __syncthreads();
  if (tid < 128) {
    const int m = tid;
    int y = bound[m];
    path_out[m * 32 + 31] = (float)y;
    for (int tt = 30; tt >= 0; --tt) {
      y = bptr[(size_t)(m * 32 + tt + 1) * 32 + y];
      path_out[m * 32 + tt] = (float)y;
    }
  }
}

extern "C" void kernel_launch(void* const* d_in, const int* in_sizes, int n_in,
                              void* d_out, int out_size, void* d_ws, size_t ws_size,
                              hipStream_t stream)
{
  const int* sent    = (const int*)d_in[0];
  const float* embed = (const float*)d_in[1];
  const float* Wih_f = (const float*)d_in[2];
  const float* Whh_f = (const float*)d_in[3];
  const float* b_f   = (const float*)d_in[4];
  const float* Wih_b = (const float*)d_in[5];
  const float* Whh_b = (const float*)d_in[6];
  const float* b_b   = (const float*)d_in[7];
  const float* W_out = (const float*)d_in[8];
  const float* b_out = (const float*)d_in[9];
  const float* trans = (const float*)d_in[10];
  const float* h0    = (const float*)d_in[11];
  const float* c0    = (const float*)d_in[12];

  float* W = (float*)d_ws;
  float* zxF = W;                                   // 16 MB
  float* zxB = zxF + (size_t)T_LEN * G4;            // 16 MB
  float* feats = zxB + (size_t)T_LEN * G4;          // 512 KB
  __hip_bfloat16* hhF = (__hip_bfloat16*)(feats + (size_t)T_LEN * KTAGS);  // 2 MB
  __hip_bfloat16* hhB = hhF + (size_t)T_LEN * H2;   // 2 MB
  float* hxchg = (float*)(hhB + (size_t)T_LEN * H2);  // 2*2*256 floats
  int* ctl = (int*)(hxchg + 1024);                  // 4 KB control
  int* bestIdx = ctl + 1024;
  unsigned char* bptr = (unsigned char*)(bestIdx + 16);  // 128 KB
  unsigned char* fmap = bptr + (size_t)T_LEN * KTAGS;    // 4 KB

  float* out = (float*)d_out;  // out[0]=path_score, out[1..4096]=path tags

  hipMemsetAsync(ctl, 0, 4096, stream);  // election counters + progress flags

  zx_gemm<<<dim3(T_LEN / 8, 2), 256, 0, stream>>>(sent, embed, Wih_f, b_f, Wih_b, b_b, zxF, zxB);
  lstm_kernel<<<64, 512, 0, stream>>>(Whh_f, Whh_b, h0, c0, zxF, zxB, hxchg, hhF, hhB, ctl);
  feat_kernel<<<T_LEN / 8, 256, 0, stream>>>(hhF, hhB, W_out, b_out, feats);
  viterbi_fwd<<<1, 1024, 0, stream>>>(feats, trans, bptr, out, bestIdx);
  vit_compose<<<128, 64, 0, stream>>>(bptr, fmap);
  vit_backtrace<<<1, 256, 0, stream>>>(bptr, fmap, bestIdx, out + 1);
}